// Round 1
// baseline (878.851 us; speedup 1.0000x reference)
//
#include <hip/hip_runtime.h>
#include <math.h>

#define BB 4
#define NN 2048
#define DD 512
#define HH 8
#define EE 64
#define BHNE (BB*HH*NN*EE)   // 4,194,304 elements per tensor

// 4x4 outer-product accumulate: ACC[i][j] += A.i * W.j
#define FMA16(ACC, A, W) do { \
  ACC[0][0] += (A).x*(W).x; ACC[0][1] += (A).x*(W).y; ACC[0][2] += (A).x*(W).z; ACC[0][3] += (A).x*(W).w; \
  ACC[1][0] += (A).y*(W).x; ACC[1][1] += (A).y*(W).y; ACC[1][2] += (A).y*(W).z; ACC[1][3] += (A).y*(W).w; \
  ACC[2][0] += (A).z*(W).x; ACC[2][1] += (A).z*(W).y; ACC[2][2] += (A).z*(W).z; ACC[2][3] += (A).z*(W).w; \
  ACC[3][0] += (A).w*(W).x; ACC[3][1] += (A).w*(W).y; ACC[3][2] += (A).w*(W).z; ACC[3][3] += (A).w*(W).w; \
} while(0)

// ---------------------------------------------------------------------------
// Kernel 1: per-head projections.  Q = x2·Wq^T, K = x1·Wk^T, V = v·Wv^T
// Output layout ws: [p][B][H][N][E], p in {0:Q, 1:K, 2:V}
// Block: 256 threads, computes one 64(n) x 64(e) tile for one (b,h,p).
// ---------------------------------------------------------------------------
__global__ __launch_bounds__(256) void proj_kernel(
    const float* __restrict__ x1, const float* __restrict__ x2,
    const float* __restrict__ vin,
    const float* __restrict__ Wq, const float* __restrict__ Wk,
    const float* __restrict__ Wv, float* __restrict__ ws)
{
  const int ntile = blockIdx.x;        // N/64
  const int bh    = blockIdx.y;        // B*H
  const int p     = blockIdx.z;        // 0=q,1=k,2=v
  const int b = bh >> 3, h = bh & 7;

  const float* X = (p == 0) ? x2 : (p == 1) ? x1 : vin;
  const float* W = (p == 0) ? Wq : (p == 1) ? Wk : Wv;
  float* O = ws + (size_t)p * BHNE;

  __shared__ float xT[64][68];   // [d][n], pad 68: rows 16B-aligned, 2-way banks on read
  __shared__ float wT[64][68];   // [d][e]

  const int t  = threadIdx.x;
  const int tx = t & 15, ty = t >> 4;
  const int n0 = ntile * 64;

  float acc[4][4] = {};

  for (int dc = 0; dc < DD; dc += 64) {
    __syncthreads();
    #pragma unroll
    for (int rr = 0; rr < 64; rr += 16) {
      const int r = ty + rr;
      float4 xv = *(const float4*)&X[((size_t)b*NN + n0 + r)*DD + dc + tx*4];
      xT[tx*4+0][r] = xv.x; xT[tx*4+1][r] = xv.y;
      xT[tx*4+2][r] = xv.z; xT[tx*4+3][r] = xv.w;
      float4 wv = *(const float4*)&W[((size_t)h*EE + r)*DD + dc + tx*4];
      wT[tx*4+0][r] = wv.x; wT[tx*4+1][r] = wv.y;
      wT[tx*4+2][r] = wv.z; wT[tx*4+3][r] = wv.w;
    }
    __syncthreads();
    #pragma unroll 8
    for (int d = 0; d < 64; ++d) {
      float4 a = *(const float4*)&xT[d][ty*4];
      float4 w = *(const float4*)&wT[d][tx*4];
      FMA16(acc, a, w);
    }
  }

  #pragma unroll
  for (int i = 0; i < 4; ++i) {
    float4 o4 = make_float4(acc[i][0], acc[i][1], acc[i][2], acc[i][3]);
    *(float4*)&O[((size_t)bh*NN + n0 + ty*4 + i)*EE + tx*4] = o4;
  }
}

// ---------------------------------------------------------------------------
// Kernel 2: flash-style attention per (b,h).  rep[b][n][h][e] output layout.
// Block: 256 threads handles one 64-row Q tile; iterates 32 K/V tiles.
// Thread (tx,ty): S rows i = 4*ty..+3, cols j = 4*tx..+3.  Row statistics
// reduced over the 16 lanes sharing ty (consecutive lanes -> shfl_xor 1,2,4,8).
// ---------------------------------------------------------------------------
__global__ __launch_bounds__(256) void attn_kernel(
    const float* __restrict__ ws, float* __restrict__ rep)
{
  const int itile = blockIdx.x;        // N/64
  const int bh    = blockIdx.y;        // B*H
  const int b = bh >> 3, h = bh & 7;

  const float* Q = ws + 0ul*BHNE + (size_t)bh * NN * EE;
  const float* K = ws + 1ul*BHNE + (size_t)bh * NN * EE;
  const float* V = ws + 2ul*BHNE + (size_t)bh * NN * EE;

  __shared__ float qT[64][68];   // [e][i]
  __shared__ float kT[64][68];   // [e][j]
  __shared__ float vs[64][68];   // [j][e]
  __shared__ float pT[64][68];   // [j][i]

  const int t  = threadIdx.x;
  const int tx = t & 15, ty = t >> 4;

  // Stage Q tile transposed (visible after the sync at top of first j-tile).
  #pragma unroll
  for (int rr = 0; rr < 64; rr += 16) {
    const int r = ty + rr;
    float4 qv = *(const float4*)&Q[((size_t)itile*64 + r)*EE + tx*4];
    qT[tx*4+0][r] = qv.x; qT[tx*4+1][r] = qv.y;
    qT[tx*4+2][r] = qv.z; qT[tx*4+3][r] = qv.w;
  }

  float m_[4], l_[4], o_[4][4];
  #pragma unroll
  for (int i = 0; i < 4; ++i) {
    m_[i] = -INFINITY; l_[i] = 0.f;
    o_[i][0] = o_[i][1] = o_[i][2] = o_[i][3] = 0.f;
  }

  for (int jt = 0; jt < NN; jt += 64) {
    __syncthreads();   // prev iter's reads of kT/vs/pT complete; qT staging complete
    #pragma unroll
    for (int rr = 0; rr < 64; rr += 16) {
      const int r = ty + rr;
      float4 kv = *(const float4*)&K[((size_t)jt + r)*EE + tx*4];
      kT[tx*4+0][r] = kv.x; kT[tx*4+1][r] = kv.y;
      kT[tx*4+2][r] = kv.z; kT[tx*4+3][r] = kv.w;
      float4 vv = *(const float4*)&V[((size_t)jt + r)*EE + tx*4];
      *(float4*)&vs[r][tx*4] = vv;
    }
    __syncthreads();

    // S = Q K^T / sqrt(E)
    float s[4][4] = {};
    #pragma unroll 8
    for (int e = 0; e < 64; ++e) {
      float4 qa = *(const float4*)&qT[e][ty*4];
      float4 kb = *(const float4*)&kT[e][tx*4];
      FMA16(s, qa, kb);
    }

    // Online softmax update
    float mt[4], rs[4], al[4];
    #pragma unroll
    for (int i = 0; i < 4; ++i) {
      s[i][0] *= 0.125f; s[i][1] *= 0.125f; s[i][2] *= 0.125f; s[i][3] *= 0.125f;
      mt[i] = fmaxf(fmaxf(s[i][0], s[i][1]), fmaxf(s[i][2], s[i][3]));
    }
    #pragma unroll
    for (int off = 1; off < 16; off <<= 1) {
      #pragma unroll
      for (int i = 0; i < 4; ++i)
        mt[i] = fmaxf(mt[i], __shfl_xor(mt[i], off, 64));
    }
    #pragma unroll
    for (int i = 0; i < 4; ++i) {
      const float mn = fmaxf(m_[i], mt[i]);
      al[i] = __expf(m_[i] - mn);          // first tile: exp(-inf) = 0
      m_[i] = mn;
      float r = 0.f;
      #pragma unroll
      for (int j = 0; j < 4; ++j) {
        const float pv = __expf(s[i][j] - mn);
        s[i][j] = pv;
        r += pv;
      }
      rs[i] = r;
    }
    #pragma unroll
    for (int off = 1; off < 16; off <<= 1) {
      #pragma unroll
      for (int i = 0; i < 4; ++i)
        rs[i] += __shfl_xor(rs[i], off, 64);
    }
    #pragma unroll
    for (int i = 0; i < 4; ++i) {
      l_[i] = l_[i] * al[i] + rs[i];
      o_[i][0] *= al[i]; o_[i][1] *= al[i]; o_[i][2] *= al[i]; o_[i][3] *= al[i];
    }

    // P -> LDS transposed for the PV outer-product
    #pragma unroll
    for (int i = 0; i < 4; ++i)
      #pragma unroll
      for (int j = 0; j < 4; ++j)
        pT[tx*4+j][ty*4+i] = s[i][j];
    __syncthreads();

    // O += P V
    #pragma unroll 8
    for (int j = 0; j < 64; ++j) {
      float4 pa = *(const float4*)&pT[j][ty*4];
      float4 vb = *(const float4*)&vs[j][tx*4];
      FMA16(o_, pa, vb);
    }
  }

  // Finalize and write rep[b][n][h][e]
  #pragma unroll
  for (int i = 0; i < 4; ++i) {
    const float inv = 1.0f / l_[i];
    float4 o4 = make_float4(o_[i][0]*inv, o_[i][1]*inv, o_[i][2]*inv, o_[i][3]*inv);
    *(float4*)&rep[(((size_t)b*NN + itile*64 + ty*4 + i)*HH + h)*EE + tx*4] = o4;
  }
}

// ---------------------------------------------------------------------------
// Kernel 3: output projection with head-sum folded into K dim:
// out[r][o] = sum_{h,e} rep[r][h*64+e] * Wo[h][o][e],  r = b*N+n
// ---------------------------------------------------------------------------
__global__ __launch_bounds__(256) void outproj_kernel(
    const float* __restrict__ rep, const float* __restrict__ Wo,
    float* __restrict__ out)
{
  const int rtile = blockIdx.x;   // B*N/64 = 128
  const int otile = blockIdx.y;   // D/64 = 8

  __shared__ float aT[64][68];    // [e][n]
  __shared__ float wT[64][68];    // [e][o]

  const int t  = threadIdx.x;
  const int tx = t & 15, ty = t >> 4;

  float acc[4][4] = {};

  for (int c = 0; c < HH; ++c) {  // chunk of 64 (h,e) pairs == head c
    __syncthreads();
    #pragma unroll
    for (int rr = 0; rr < 64; rr += 16) {
      const int r = ty + rr;
      float4 av = *(const float4*)&rep[((size_t)rtile*64 + r)*DD + c*EE + tx*4];
      aT[tx*4+0][r] = av.x; aT[tx*4+1][r] = av.y;
      aT[tx*4+2][r] = av.z; aT[tx*4+3][r] = av.w;
      float4 wv = *(const float4*)&Wo[((size_t)c*DD + otile*64 + r)*EE + tx*4];
      wT[tx*4+0][r] = wv.x; wT[tx*4+1][r] = wv.y;
      wT[tx*4+2][r] = wv.z; wT[tx*4+3][r] = wv.w;
    }
    __syncthreads();
    #pragma unroll 8
    for (int d = 0; d < 64; ++d) {
      float4 a = *(const float4*)&aT[d][ty*4];
      float4 w = *(const float4*)&wT[d][tx*4];
      FMA16(acc, a, w);
    }
  }

  #pragma unroll
  for (int i = 0; i < 4; ++i) {
    float4 o4 = make_float4(acc[i][0], acc[i][1], acc[i][2], acc[i][3]);
    *(float4*)&out[((size_t)rtile*64 + ty*4 + i)*DD + otile*64 + tx*4] = o4;
  }
}

// ---------------------------------------------------------------------------
extern "C" void kernel_launch(void* const* d_in, const int* in_sizes, int n_in,
                              void* d_out, int out_size, void* d_ws, size_t ws_size,
                              hipStream_t stream)
{
  const float* x1 = (const float*)d_in[0];
  const float* x2 = (const float*)d_in[1];
  const float* vv = (const float*)d_in[2];
  const float* Wq = (const float*)d_in[3];
  const float* Wk = (const float*)d_in[4];
  const float* Wv = (const float*)d_in[5];
  const float* Wo = (const float*)d_in[6];
  float* out = (float*)d_out;
  float* ws  = (float*)d_ws;           // [Q|K|V|rep], 4 * 16 MB = 64 MB
  float* rep = ws + 3ul * BHNE;

  proj_kernel   <<<dim3(NN/64, BB*HH, 3), 256, 0, stream>>>(x1, x2, vv, Wq, Wk, Wv, ws);
  attn_kernel   <<<dim3(NN/64, BB*HH),    256, 0, stream>>>(ws, rep);
  outproj_kernel<<<dim3(BB*NN/64, DD/64), 256, 0, stream>>>(rep, Wo, out);
}

// Round 2
// 410.851 us; speedup vs baseline: 2.1391x; 2.1391x over previous
//
#include <hip/hip_runtime.h>
#include <math.h>

#define NN 2048
#define DD 512
#define HH 8
#define EE 64

typedef unsigned short u16;
typedef __attribute__((ext_vector_type(8))) short bf16x8;
typedef __attribute__((ext_vector_type(4))) float f32x4;

#define MFMA(a,b,c) __builtin_amdgcn_mfma_f32_16x16x32_bf16((a),(b),(c),0,0,0)

// round-to-nearest-even fp32 -> bf16 (inputs are finite, no NaN handling needed)
__device__ __forceinline__ unsigned rnd1(float x){
  unsigned u = __float_as_uint(x);
  return (u + 0x7fffu + ((u >> 16) & 1u)) >> 16;
}
__device__ __forceinline__ unsigned pk2(float a, float b){
  return rnd1(a) | (rnd1(b) << 16);
}
// hi/lo bf16 split: x ~= hi + lo to ~2^-16 relative
__device__ __forceinline__ void split1(float x, u16 &hi, u16 &lo){
  unsigned h = rnd1(x);
  float hf = __uint_as_float(h << 16);
  hi = (u16)h;
  lo = (u16)rnd1(x - hf);
}
union I4V { int4 i; bf16x8 v; };
__device__ __forceinline__ bf16x8 ld_frag(const u16* p){
  I4V u; u.i = *(const int4*)p; return u.v;
}
__device__ __forceinline__ bf16x8 mk_frag(int a, int b, int c, int d){
  I4V u; u.i = make_int4(a,b,c,d); return u.v;
}
__device__ __forceinline__ bf16x8 cvt_frag(const float4 &fa, const float4 &fb){
  return mk_frag(pk2(fa.x,fa.y), pk2(fa.z,fa.w), pk2(fb.x,fb.y), pk2(fb.z,fb.w));
}
__device__ __forceinline__ void split_frag(const float4 &fa, const float4 &fb,
                                           bf16x8 &h8, bf16x8 &l8){
  u16 h[8], l[8];
  const float f[8] = {fa.x,fa.y,fa.z,fa.w,fb.x,fb.y,fb.z,fb.w};
  #pragma unroll
  for (int i = 0; i < 8; ++i) split1(f[i], h[i], l[i]);
  h8 = mk_frag(h[0]|(h[1]<<16), h[2]|(h[3]<<16), h[4]|(h[5]<<16), h[6]|(h[7]<<16));
  l8 = mk_frag(l[0]|(l[1]<<16), l[2]|(l[3]<<16), l[4]|(l[5]<<16), l[6]|(l[7]<<16));
}

// ---------------------------------------------------------------------------
// Weight pre-convert: Wq*scale, Wk -> bf16; Wv -> hi/lo bf16; Wo -> bf16
// transposed to [o][h*64+e].  262144 elements per segment, grid (1024,4).
// ---------------------------------------------------------------------------
__global__ __launch_bounds__(256) void precvt_kernel(
    const float* __restrict__ Wq, const float* __restrict__ Wk,
    const float* __restrict__ Wv, const float* __restrict__ Wo,
    u16* __restrict__ wqb, u16* __restrict__ wkb,
    u16* __restrict__ wvh, u16* __restrict__ wvl, u16* __restrict__ wob)
{
  const int idx = blockIdx.x * 256 + threadIdx.x;   // 0..262143
  const int seg = blockIdx.y;
  if (seg == 0) {
    // fold 1/sqrt(E) * log2(e) into Wq so attention uses exp2 directly
    wqb[idx] = (u16)rnd1(Wq[idx] * 0.18033688011112042f);
  } else if (seg == 1) {
    wkb[idx] = (u16)rnd1(Wk[idx]);
  } else if (seg == 2) {
    u16 h, l; split1(Wv[idx], h, l); wvh[idx] = h; wvl[idx] = l;
  } else {
    const int h = idx >> 15, o = (idx >> 6) & 511, e = idx & 63;
    wob[(size_t)o * 512 + h * 64 + e] = (u16)rnd1(Wo[idx]);
  }
}

// ---------------------------------------------------------------------------
// Q/K projection: Qb[bh][n][e] = bf16( sum_d X[b][n][d] * W[h][e][d] )
// p=0: X=x2,W=wqb(scaled)->Qb ; p=1: X=x1,W=wkb->Kb.
// Block 256 = 4 waves; wave w handles 16 n-rows; MFMA A=x rows, B=W rows.
// ---------------------------------------------------------------------------
__global__ __launch_bounds__(256) void qkproj_kernel(
    const float* __restrict__ x1, const float* __restrict__ x2,
    const u16* __restrict__ wqb, const u16* __restrict__ wkb,
    u16* __restrict__ Qb, u16* __restrict__ Kb)
{
  const int tid = threadIdx.x, w = tid >> 6, lane = tid & 63;
  const int jl = lane & 15, q = lane >> 4;
  const int ntile = blockIdx.x, bh = blockIdx.y, p = blockIdx.z;
  const int b = bh >> 3, h = bh & 7;

  const float* X = p ? x1 : x2;
  const u16*   W = (p ? wkb : wqb) + (size_t)h * EE * DD;
  u16*         O = (p ? Kb : Qb) + (size_t)bh * NN * EE;

  const int n0 = ntile * 64 + w * 16;
  const float* xr = X + ((size_t)b * NN + n0 + jl) * DD;

  f32x4 acc[4];
  #pragma unroll
  for (int i = 0; i < 4; ++i) acc[i] = (f32x4){0.f,0.f,0.f,0.f};

  for (int kc = 0; kc < 16; ++kc) {
    const int d0 = kc * 32 + q * 8;
    float4 fa = *(const float4*)(xr + d0);
    float4 fb = *(const float4*)(xr + d0 + 4);
    bf16x8 af = cvt_frag(fa, fb);
    #pragma unroll
    for (int es = 0; es < 4; ++es) {
      bf16x8 bf = ld_frag(W + (size_t)(es * 16 + jl) * DD + d0);
      acc[es] = MFMA(af, bf, acc[es]);
    }
  }
  #pragma unroll
  for (int es = 0; es < 4; ++es)
    #pragma unroll
    for (int r = 0; r < 4; ++r)
      O[(size_t)(n0 + q * 4 + r) * EE + es * 16 + jl] = (u16)rnd1(acc[es][r]);
}

// ---------------------------------------------------------------------------
// V projection (transposed, hi/lo): Vt[bh][jt][e][j in 64] = sum_d Wv[e][d]*v[n][d]
// 3-term split GEMM: Ah*Bh + Ah*Bl + Al*Bh (A=Wv hi/lo, B=v hi/lo).
// ---------------------------------------------------------------------------
__global__ __launch_bounds__(256) void vproj_kernel(
    const float* __restrict__ v,
    const u16* __restrict__ wvh, const u16* __restrict__ wvl,
    u16* __restrict__ Vth, u16* __restrict__ Vtl)
{
  const int tid = threadIdx.x, w = tid >> 6, lane = tid & 63;
  const int jl = lane & 15, q = lane >> 4;
  const int ntile = blockIdx.x, bh = blockIdx.y;
  const int b = bh >> 3, h = bh & 7;

  const float* vr = v + ((size_t)b * NN + ntile * 64 + w * 16 + jl) * DD;
  const u16* wh = wvh + (size_t)h * EE * DD;
  const u16* wl = wvl + (size_t)h * EE * DD;

  f32x4 acc[4];
  #pragma unroll
  for (int i = 0; i < 4; ++i) acc[i] = (f32x4){0.f,0.f,0.f,0.f};

  for (int kc = 0; kc < 16; ++kc) {
    const int d0 = kc * 32 + q * 8;
    float4 fa = *(const float4*)(vr + d0);
    float4 fb = *(const float4*)(vr + d0 + 4);
    bf16x8 bh8, bl8;
    split_frag(fa, fb, bh8, bl8);
    #pragma unroll
    for (int m = 0; m < 4; ++m) {
      bf16x8 ah = ld_frag(wh + (size_t)(m * 16 + jl) * DD + d0);
      bf16x8 al = ld_frag(wl + (size_t)(m * 16 + jl) * DD + d0);
      acc[m] = MFMA(ah, bh8, acc[m]);
      acc[m] = MFMA(ah, bl8, acc[m]);
      acc[m] = MFMA(al, bh8, acc[m]);
    }
  }
  const size_t base = ((size_t)bh * 32 + ntile) * 4096;
  const int jloc = w * 16 + jl;
  #pragma unroll
  for (int m = 0; m < 4; ++m)
    #pragma unroll
    for (int r = 0; r < 4; ++r) {
      const int e = m * 16 + q * 4 + r;
      u16 hi, lo; split1(acc[m][r], hi, lo);
      Vth[base + e * 64 + jloc] = hi;
      Vtl[base + e * 64 + jloc] = lo;
    }
}

// ---------------------------------------------------------------------------
// Attention: per (bh, 64-row i-tile).  4 waves split the j range (512 each).
// S^T = K*Q^T (no max-tracking: scores are O(1), exp2 safe).  P round-trips
// through per-wave-private LDS into A-operand layout; PV reads V^T hi/lo
// fragments straight from global (L1/L2).  Block-level combine at the end,
// normalized by l, output rep as hi/lo bf16 [b][n][h][e].
// ---------------------------------------------------------------------------
__global__ __launch_bounds__(256, 2) void attn_kernel(
    const u16* __restrict__ Qb, const u16* __restrict__ Kb,
    const u16* __restrict__ Vth, const u16* __restrict__ Vtl,
    u16* __restrict__ RepH, u16* __restrict__ RepL)
{
  __shared__ union {
    short P[4][64][76];       // per-wave 64x64 P tile, stride 76 bf16 (152 B)
    float slab[2][64 * 65];   // combine scratch (overlays dead P regions)
  } sh;
  __shared__ float lbuf[4][64];

  const int tid = threadIdx.x, w = tid >> 6, lane = tid & 63;
  const int jl = lane & 15, q = lane >> 4;
  const int bx = blockIdx.x;
  const int itile = bx >> 5;        // itile slow: each XCD sees bh == xcd (mod 8) -> K/V L2-resident
  const int bh = bx & 31;
  const int b = bh >> 3, h = bh & 7;

  // Q fragments, held in registers for the whole kernel
  const u16* Qp = Qb + ((size_t)bh * NN + itile * 64) * EE;
  bf16x8 qf[4][2];
  #pragma unroll
  for (int is = 0; is < 4; ++is)
    #pragma unroll
    for (int kh = 0; kh < 2; ++kh)
      qf[is][kh] = ld_frag(Qp + (is * 16 + jl) * EE + kh * 32 + q * 8);

  const u16* Kp  = Kb  + ((size_t)bh * NN + w * 512) * EE;
  const u16* Vhp = Vth + ((size_t)bh * 32 + w * 8) * 4096;
  const u16* Vlp = Vtl + ((size_t)bh * 32 + w * 8) * 4096;

  char* pw = (char*)&sh.P[0][0][0] + w * 9728 + jl * 152 + q * 8;        // P write base
  const char* pr = (const char*)&sh.P[0][0][0] + w * 9728 + jl * 152 + q * 16; // P read base

  f32x4 acc[4][4];
  #pragma unroll
  for (int m = 0; m < 4; ++m)
    #pragma unroll
    for (int e = 0; e < 4; ++e) acc[m][e] = (f32x4){0.f,0.f,0.f,0.f};
  float lac[4] = {0.f, 0.f, 0.f, 0.f};

  for (int jt = 0; jt < 8; ++jt) {
    // ---- S^T = K*Q^T, exp2, P -> LDS (A-operand layout) ----
    #pragma unroll
    for (int jm = 0; jm < 4; ++jm) {
      bf16x8 k0 = ld_frag(Kp + (jm * 16 + jl) * EE + q * 8);
      bf16x8 k1 = ld_frag(Kp + (jm * 16 + jl) * EE + 32 + q * 8);
      #pragma unroll
      for (int is = 0; is < 4; ++is) {
        f32x4 c = (f32x4){0.f,0.f,0.f,0.f};
        c = MFMA(k0, qf[is][0], c);
        c = MFMA(k1, qf[is][1], c);
        float e0 = exp2f(c[0]), e1 = exp2f(c[1]);
        float e2 = exp2f(c[2]), e3 = exp2f(c[3]);
        lac[is] += (e0 + e1) + (e2 + e3);
        int2 pv; pv.x = pk2(e0, e1); pv.y = pk2(e2, e3);
        *(int2*)(pw + is * 2432 + jm * 32) = pv;
      }
    }
    // ---- rep += P * (Vhi + Vlo) ----
    #pragma unroll
    for (int m = 0; m < 4; ++m) {
      int2 a0 = *(const int2*)(pr + m * 2432);
      int2 a1 = *(const int2*)(pr + m * 2432 + 8);
      int2 a2 = *(const int2*)(pr + m * 2432 + 64);
      int2 a3 = *(const int2*)(pr + m * 2432 + 72);
      bf16x8 p0 = mk_frag(a0.x, a0.y, a1.x, a1.y);
      bf16x8 p1 = mk_frag(a2.x, a2.y, a3.x, a3.y);
      #pragma unroll
      for (int es = 0; es < 4; ++es) {
        const u16* vb  = Vhp + (es * 16 + jl) * 64 + q * 8;
        const u16* vbl = Vlp + (es * 16 + jl) * 64 + q * 8;
        acc[m][es] = MFMA(p0, ld_frag(vb), acc[m][es]);
        acc[m][es] = MFMA(p0, ld_frag(vbl), acc[m][es]);
        acc[m][es] = MFMA(p1, ld_frag(vb + 32), acc[m][es]);
        acc[m][es] = MFMA(p1, ld_frag(vbl + 32), acc[m][es]);
      }
    }
    Kp += 64 * EE; Vhp += 4096; Vlp += 4096;
  }

  // ---- l reduction within wave (sum over quads), publish to LDS ----
  #pragma unroll
  for (int is = 0; is < 4; ++is) {
    float lv = lac[is];
    lv += __shfl_xor(lv, 16, 64);
    lv += __shfl_xor(lv, 32, 64);
    if (lane < 16) lbuf[w][is * 16 + lane] = lv;
  }
  __syncthreads();   // all waves done with their P regions; slabs now safe

  // ---- block combine: acc(w0) += acc(w1..w3) via 2 LDS slabs ----
  if (w >= 2) {
    float* s = sh.slab[w - 2];
    #pragma unroll
    for (int m = 0; m < 4; ++m)
      #pragma unroll
      for (int es = 0; es < 4; ++es)
        #pragma unroll
        for (int r = 0; r < 4; ++r)
          s[(m * 16 + q * 4 + r) * 65 + es * 16 + jl] = acc[m][es][r];
  }
  __syncthreads();
  if (w < 2) {
    const float* s = sh.slab[w];
    #pragma unroll
    for (int m = 0; m < 4; ++m)
      #pragma unroll
      for (int es = 0; es < 4; ++es)
        #pragma unroll
        for (int r = 0; r < 4; ++r)
          acc[m][es][r] += s[(m * 16 + q * 4 + r) * 65 + es * 16 + jl];
  }
  __syncthreads();
  if (w == 1) {
    float* s = sh.slab[0];
    #pragma unroll
    for (int m = 0; m < 4; ++m)
      #pragma unroll
      for (int es = 0; es < 4; ++es)
        #pragma unroll
        for (int r = 0; r < 4; ++r)
          s[(m * 16 + q * 4 + r) * 65 + es * 16 + jl] = acc[m][es][r];
  }
  __syncthreads();
  if (w == 0) {
    const float* s = sh.slab[0];
    #pragma unroll
    for (int m = 0; m < 4; ++m) {
      float il[4];
      #pragma unroll
      for (int r = 0; r < 4; ++r) {
        const int i = m * 16 + q * 4 + r;
        il[r] = 1.0f / (lbuf[0][i] + lbuf[1][i] + lbuf[2][i] + lbuf[3][i]);
      }
      #pragma unroll
      for (int es = 0; es < 4; ++es)
        #pragma unroll
        for (int r = 0; r < 4; ++r) {
          float val = (acc[m][es][r] + s[(m * 16 + q * 4 + r) * 65 + es * 16 + jl]) * il[r];
          u16 hi, lo; split1(val, hi, lo);
          const size_t off = (((size_t)b * NN + itile * 64 + m * 16 + q * 4 + r) * HH + h) * EE
                             + es * 16 + jl;
          RepH[off] = hi; RepL[off] = lo;
        }
    }
  }
}

// ---------------------------------------------------------------------------
// Output projection: out[r][o] = sum_k (repH+repL)[r][k] * Wo'[o][k]
// 2-term split GEMM (rep hi/lo x Wo bf16).
// ---------------------------------------------------------------------------
__global__ __launch_bounds__(256) void outproj_kernel(
    const u16* __restrict__ RepH, const u16* __restrict__ RepL,
    const u16* __restrict__ wob, float* __restrict__ out)
{
  const int tid = threadIdx.x, w = tid >> 6, lane = tid & 63;
  const int jl = lane & 15, q = lane >> 4;
  const int rtile = blockIdx.x, otile = blockIdx.y;
  const int r0 = rtile * 64 + w * 16;

  const u16* ah_row = RepH + (size_t)(r0 + jl) * DD;
  const u16* al_row = RepL + (size_t)(r0 + jl) * DD;

  f32x4 acc[4];
  #pragma unroll
  for (int i = 0; i < 4; ++i) acc[i] = (f32x4){0.f,0.f,0.f,0.f};

  for (int kc = 0; kc < 16; ++kc) {
    const int k0 = kc * 32 + q * 8;
    bf16x8 ah = ld_frag(ah_row + k0);
    bf16x8 al = ld_frag(al_row + k0);
    #pragma unroll
    for (int os = 0; os < 4; ++os) {
      bf16x8 bfr = ld_frag(wob + (size_t)(otile * 64 + os * 16 + jl) * DD + k0);
      acc[os] = MFMA(ah, bfr, acc[os]);
      acc[os] = MFMA(al, bfr, acc[os]);
    }
  }
  #pragma unroll
  for (int os = 0; os < 4; ++os)
    #pragma unroll
    for (int r = 0; r < 4; ++r)
      out[(size_t)(r0 + q * 4 + r) * DD + otile * 64 + os * 16 + jl] = acc[os][r];
}

// ---------------------------------------------------------------------------
extern "C" void kernel_launch(void* const* d_in, const int* in_sizes, int n_in,
                              void* d_out, int out_size, void* d_ws, size_t ws_size,
                              hipStream_t stream)
{
  const float* x1 = (const float*)d_in[0];
  const float* x2 = (const float*)d_in[1];
  const float* vv = (const float*)d_in[2];
  const float* Wq = (const float*)d_in[3];
  const float* Wk = (const float*)d_in[4];
  const float* Wv = (const float*)d_in[5];
  const float* Wo = (const float*)d_in[6];
  float* out = (float*)d_out;

  char* W = (char*)d_ws;
  u16* wqb = (u16*)(W);
  u16* wkb = (u16*)(W + 524288);
  u16* wvh = (u16*)(W + 1048576);
  u16* wvl = (u16*)(W + 1572864);
  u16* wob = (u16*)(W + 2097152);
  u16* Qb  = (u16*)(W + 2621440);
  u16* Kb  = (u16*)(W + 2621440 + 1ul * 8388608);
  u16* Vth = (u16*)(W + 2621440 + 2ul * 8388608);
  u16* Vtl = (u16*)(W + 2621440 + 3ul * 8388608);
  u16* RepH= (u16*)(W + 2621440 + 4ul * 8388608);
  u16* RepL= (u16*)(W + 2621440 + 5ul * 8388608);

  precvt_kernel <<<dim3(1024, 4), 256, 0, stream>>>(Wq, Wk, Wv, Wo, wqb, wkb, wvh, wvl, wob);
  qkproj_kernel <<<dim3(32, 32, 2), 256, 0, stream>>>(x1, x2, wqb, wkb, Qb, Kb);
  vproj_kernel  <<<dim3(32, 32), 256, 0, stream>>>(vv, wvh, wvl, Vth, Vtl);
  attn_kernel   <<<dim3(1024), 256, 0, stream>>>(Qb, Kb, Vth, Vtl, RepH, RepL);
  outproj_kernel<<<dim3(128, 8), 256, 0, stream>>>(RepH, RepL, wob, out);
}

// Round 3
// 298.226 us; speedup vs baseline: 2.9469x; 1.3777x over previous
//
#include <hip/hip_runtime.h>
#include <math.h>

#define NN 2048
#define DD 512
#define HH 8
#define EE 64

typedef unsigned short u16;
typedef __attribute__((ext_vector_type(8))) short bf16x8;
typedef __attribute__((ext_vector_type(4))) float f32x4;

#define MFMA(a,b,c) __builtin_amdgcn_mfma_f32_16x16x32_bf16((a),(b),(c),0,0,0)

__device__ __forceinline__ float fexp2(float x){
#if __has_builtin(__builtin_amdgcn_exp2f)
  return __builtin_amdgcn_exp2f(x);
#else
  return exp2f(x);
#endif
}

// round-to-nearest-even fp32 -> bf16 (finite inputs only)
__device__ __forceinline__ unsigned rnd1(float x){
  unsigned u = __float_as_uint(x);
  return (u + 0x7fffu + ((u >> 16) & 1u)) >> 16;
}
__device__ __forceinline__ unsigned pk2(float a, float b){
  return rnd1(a) | (rnd1(b) << 16);
}
// hi/lo bf16 split: x ~= hi + lo to ~2^-16 relative
__device__ __forceinline__ void split1(float x, u16 &hi, u16 &lo){
  unsigned h = rnd1(x);
  float hf = __uint_as_float(h << 16);
  hi = (u16)h;
  lo = (u16)rnd1(x - hf);
}
union I4V { int4 i; bf16x8 v; };
__device__ __forceinline__ bf16x8 ld_frag(const u16* p){
  I4V u; u.i = *(const int4*)p; return u.v;
}
__device__ __forceinline__ bf16x8 mk_frag(int a, int b, int c, int d){
  I4V u; u.i = make_int4(a,b,c,d); return u.v;
}
__device__ __forceinline__ bf16x8 cvt_frag(const float4 &fa, const float4 &fb){
  return mk_frag(pk2(fa.x,fa.y), pk2(fa.z,fa.w), pk2(fb.x,fb.y), pk2(fb.z,fb.w));
}
__device__ __forceinline__ void split_frag(const float4 &fa, const float4 &fb,
                                           bf16x8 &h8, bf16x8 &l8){
  u16 h[8], l[8];
  const float f[8] = {fa.x,fa.y,fa.z,fa.w,fb.x,fb.y,fb.z,fb.w};
  #pragma unroll
  for (int i = 0; i < 8; ++i) split1(f[i], h[i], l[i]);
  h8 = mk_frag(h[0]|(h[1]<<16), h[2]|(h[3]<<16), h[4]|(h[5]<<16), h[6]|(h[7]<<16));
  l8 = mk_frag(l[0]|(l[1]<<16), l[2]|(l[3]<<16), l[4]|(l[5]<<16), l[6]|(l[7]<<16));
}

// ---------------------------------------------------------------------------
// Fused Q/K/V projection.  Per block: one (ntile 64 rows, bh, p).
// W chunk (64e x 64d) is converted fp32->bf16 (p==0 pre-scaled; p==2 hi/lo
// split) into LDS once per chunk, shared by all 4 waves.  x rows stay
// per-wave global loads (unique data).  A=W(LDS), B=x(global) so the MFMA
// D-tile has rows=e, cols=n  ->  packed stores.
//   p=0: Qb[bh][n][e]   (Wq pre-scaled by log2(e)/sqrt(E))
//   p=1: Kb[bh][n][e]
//   p=2: Vth/Vtl[bh][ntile][e][j64]   (transposed, hi/lo)
// ---------------------------------------------------------------------------
__global__ __launch_bounds__(256) void qkvproj_kernel(
    const float* __restrict__ x1, const float* __restrict__ x2,
    const float* __restrict__ vin,
    const float* __restrict__ Wq, const float* __restrict__ Wk,
    const float* __restrict__ Wv,
    u16* __restrict__ Qb, u16* __restrict__ Kb,
    u16* __restrict__ Vth, u16* __restrict__ Vtl)
{
  __shared__ u16 wt[2][64][72];   // [hi/lo][e][d-chunk], 144B rows (16B aligned)

  const int t = threadIdx.x, w = t >> 6, lane = t & 63;
  const int jl = lane & 15, q = lane >> 4;
  const int ntile = blockIdx.x, bh = blockIdx.y, p = blockIdx.z;
  const int b = bh >> 3, h = bh & 7;

  const float* X = (p == 0) ? x2 : (p == 1) ? x1 : vin;
  const float* Wsrc = ((p == 0) ? Wq : (p == 1) ? Wk : Wv) + (size_t)h * EE * DD;
  const float scale = (p == 0) ? 0.18033688011112042f : 1.0f;

  const int n0 = ntile * 64;
  const float* xr = X + ((size_t)b * NN + n0 + w * 16 + jl) * DD;

  f32x4 acc[4];
  #pragma unroll
  for (int i = 0; i < 4; ++i) acc[i] = (f32x4){0.f,0.f,0.f,0.f};

  for (int ch = 0; ch < 8; ++ch) {
    __syncthreads();
    // ---- stage W chunk (coalesced fp32 read, convert, LDS) ----
    #pragma unroll
    for (int it = 0; it < 4; ++it) {
      const int e = it * 16 + (t >> 4), c = (t & 15) * 4;
      float4 f = *(const float4*)&Wsrc[(size_t)e * DD + ch * 64 + c];
      if (p == 2) {
        u16 h0,l0,h1,l1,h2,l2,h3,l3;
        split1(f.x,h0,l0); split1(f.y,h1,l1); split1(f.z,h2,l2); split1(f.w,h3,l3);
        *(uint2*)&wt[0][e][c] = make_uint2((unsigned)h0|((unsigned)h1<<16),
                                           (unsigned)h2|((unsigned)h3<<16));
        *(uint2*)&wt[1][e][c] = make_uint2((unsigned)l0|((unsigned)l1<<16),
                                           (unsigned)l2|((unsigned)l3<<16));
      } else {
        *(uint2*)&wt[0][e][c] = make_uint2(pk2(f.x*scale, f.y*scale),
                                           pk2(f.z*scale, f.w*scale));
      }
    }
    __syncthreads();
    // ---- compute ----
    #pragma unroll
    for (int kc2 = 0; kc2 < 2; ++kc2) {
      const int d0 = ch * 64 + kc2 * 32 + q * 8;
      float4 fa = *(const float4*)(xr + d0);
      float4 fb = *(const float4*)(xr + d0 + 4);
      if (p < 2) {
        bf16x8 xf = cvt_frag(fa, fb);
        #pragma unroll
        for (int es = 0; es < 4; ++es) {
          bf16x8 wf = ld_frag(&wt[0][es * 16 + jl][kc2 * 32 + q * 8]);
          acc[es] = MFMA(wf, xf, acc[es]);
        }
      } else {
        bf16x8 xh, xl;
        split_frag(fa, fb, xh, xl);
        #pragma unroll
        for (int es = 0; es < 4; ++es) {
          bf16x8 wh = ld_frag(&wt[0][es * 16 + jl][kc2 * 32 + q * 8]);
          bf16x8 wl = ld_frag(&wt[1][es * 16 + jl][kc2 * 32 + q * 8]);
          acc[es] = MFMA(wh, xh, acc[es]);
          acc[es] = MFMA(wh, xl, acc[es]);
          acc[es] = MFMA(wl, xh, acc[es]);
        }
      }
    }
  }

  if (p < 2) {
    u16* O = (p ? Kb : Qb) + (size_t)bh * NN * EE;
    const int row = n0 + w * 16 + jl;                 // D col = x-row
    #pragma unroll
    for (int es = 0; es < 4; ++es)                    // D row = e (r-consecutive)
      *(uint2*)&O[(size_t)row * EE + es * 16 + q * 4] =
          make_uint2(pk2(acc[es][0], acc[es][1]), pk2(acc[es][2], acc[es][3]));
  } else {
    const size_t base = ((size_t)bh * 32 + ntile) * 4096;
    const int j = w * 16 + jl;                        // D col = v-row
    #pragma unroll
    for (int es = 0; es < 4; ++es)
      #pragma unroll
      for (int r = 0; r < 4; ++r) {
        const int e = es * 16 + q * 4 + r;
        u16 hi, lo; split1(acc[es][r], hi, lo);
        Vth[base + e * 64 + j] = hi;
        Vtl[base + e * 64 + j] = lo;
      }
  }
}

// ---------------------------------------------------------------------------
// Attention (round-2 structure, exp via raw v_exp_f32).  Per (bh, 64-row
// i-tile); 4 waves split j.  S^T = K*Q^T, no max tracking, P through
// per-wave LDS into A-layout, PV from global V^T hi/lo, block combine.
// ---------------------------------------------------------------------------
__global__ __launch_bounds__(256, 2) void attn_kernel(
    const u16* __restrict__ Qb, const u16* __restrict__ Kb,
    const u16* __restrict__ Vth, const u16* __restrict__ Vtl,
    u16* __restrict__ RepH, u16* __restrict__ RepL)
{
  __shared__ union {
    short P[4][64][76];       // per-wave 64x64 P tile, stride 76 bf16 (152 B)
    float slab[2][64 * 65];   // combine scratch (overlays dead P regions)
  } sh;
  __shared__ float lbuf[4][64];

  const int tid = threadIdx.x, w = tid >> 6, lane = tid & 63;
  const int jl = lane & 15, q = lane >> 4;
  const int bx = blockIdx.x;
  const int itile = bx >> 5;        // bh fast: XCD sees fixed bh mod 8 -> L2 locality
  const int bh = bx & 31;
  const int b = bh >> 3, h = bh & 7;

  const u16* Qp = Qb + ((size_t)bh * NN + itile * 64) * EE;
  bf16x8 qf[4][2];
  #pragma unroll
  for (int is = 0; is < 4; ++is)
    #pragma unroll
    for (int kh = 0; kh < 2; ++kh)
      qf[is][kh] = ld_frag(Qp + (is * 16 + jl) * EE + kh * 32 + q * 8);

  const u16* Kp  = Kb  + ((size_t)bh * NN + w * 512) * EE;
  const u16* Vhp = Vth + ((size_t)bh * 32 + w * 8) * 4096;
  const u16* Vlp = Vtl + ((size_t)bh * 32 + w * 8) * 4096;

  char* pw = (char*)&sh.P[0][0][0] + w * 9728 + jl * 152 + q * 8;
  const char* pr = (const char*)&sh.P[0][0][0] + w * 9728 + jl * 152 + q * 16;

  f32x4 acc[4][4];
  #pragma unroll
  for (int m = 0; m < 4; ++m)
    #pragma unroll
    for (int e = 0; e < 4; ++e) acc[m][e] = (f32x4){0.f,0.f,0.f,0.f};
  float lac[4] = {0.f, 0.f, 0.f, 0.f};

  for (int jt = 0; jt < 8; ++jt) {
    #pragma unroll
    for (int jm = 0; jm < 4; ++jm) {
      bf16x8 k0 = ld_frag(Kp + (jm * 16 + jl) * EE + q * 8);
      bf16x8 k1 = ld_frag(Kp + (jm * 16 + jl) * EE + 32 + q * 8);
      #pragma unroll
      for (int is = 0; is < 4; ++is) {
        f32x4 c = (f32x4){0.f,0.f,0.f,0.f};
        c = MFMA(k0, qf[is][0], c);
        c = MFMA(k1, qf[is][1], c);
        float e0 = fexp2(c[0]), e1 = fexp2(c[1]);
        float e2 = fexp2(c[2]), e3 = fexp2(c[3]);
        lac[is] += (e0 + e1) + (e2 + e3);
        int2 pv; pv.x = pk2(e0, e1); pv.y = pk2(e2, e3);
        *(int2*)(pw + is * 2432 + jm * 32) = pv;
      }
    }
    #pragma unroll
    for (int m = 0; m < 4; ++m) {
      int2 a0 = *(const int2*)(pr + m * 2432);
      int2 a1 = *(const int2*)(pr + m * 2432 + 8);
      int2 a2 = *(const int2*)(pr + m * 2432 + 64);
      int2 a3 = *(const int2*)(pr + m * 2432 + 72);
      bf16x8 p0 = mk_frag(a0.x, a0.y, a1.x, a1.y);
      bf16x8 p1 = mk_frag(a2.x, a2.y, a3.x, a3.y);
      #pragma unroll
      for (int es = 0; es < 4; ++es) {
        const u16* vb  = Vhp + (es * 16 + jl) * 64 + q * 8;
        const u16* vbl = Vlp + (es * 16 + jl) * 64 + q * 8;
        acc[m][es] = MFMA(p0, ld_frag(vb), acc[m][es]);
        acc[m][es] = MFMA(p0, ld_frag(vbl), acc[m][es]);
        acc[m][es] = MFMA(p1, ld_frag(vb + 32), acc[m][es]);
        acc[m][es] = MFMA(p1, ld_frag(vbl + 32), acc[m][es]);
      }
    }
    Kp += 64 * EE; Vhp += 4096; Vlp += 4096;
  }

  #pragma unroll
  for (int is = 0; is < 4; ++is) {
    float lv = lac[is];
    lv += __shfl_xor(lv, 16, 64);
    lv += __shfl_xor(lv, 32, 64);
    if (lane < 16) lbuf[w][is * 16 + lane] = lv;
  }
  __syncthreads();

  if (w >= 2) {
    float* s = sh.slab[w - 2];
    #pragma unroll
    for (int m = 0; m < 4; ++m)
      #pragma unroll
      for (int es = 0; es < 4; ++es)
        #pragma unroll
        for (int r = 0; r < 4; ++r)
          s[(m * 16 + q * 4 + r) * 65 + es * 16 + jl] = acc[m][es][r];
  }
  __syncthreads();
  if (w < 2) {
    const float* s = sh.slab[w];
    #pragma unroll
    for (int m = 0; m < 4; ++m)
      #pragma unroll
      for (int es = 0; es < 4; ++es)
        #pragma unroll
        for (int r = 0; r < 4; ++r)
          acc[m][es][r] += s[(m * 16 + q * 4 + r) * 65 + es * 16 + jl];
  }
  __syncthreads();
  if (w == 1) {
    float* s = sh.slab[0];
    #pragma unroll
    for (int m = 0; m < 4; ++m)
      #pragma unroll
      for (int es = 0; es < 4; ++es)
        #pragma unroll
        for (int r = 0; r < 4; ++r)
          s[(m * 16 + q * 4 + r) * 65 + es * 16 + jl] = acc[m][es][r];
  }
  __syncthreads();
  if (w == 0) {
    const float* s = sh.slab[0];
    #pragma unroll
    for (int m = 0; m < 4; ++m) {
      float il[4];
      #pragma unroll
      for (int r = 0; r < 4; ++r) {
        const int i = m * 16 + q * 4 + r;
        il[r] = 1.0f / (lbuf[0][i] + lbuf[1][i] + lbuf[2][i] + lbuf[3][i]);
      }
      #pragma unroll
      for (int es = 0; es < 4; ++es)
        #pragma unroll
        for (int r = 0; r < 4; ++r) {
          float val = (acc[m][es][r] + s[(m * 16 + q * 4 + r) * 65 + es * 16 + jl]) * il[r];
          u16 hi, lo; split1(val, hi, lo);
          const size_t off = (((size_t)b * NN + itile * 64 + m * 16 + q * 4 + r) * HH + h) * EE
                             + es * 16 + jl;
          RepH[off] = hi; RepL[off] = lo;
        }
    }
  }
}

// ---------------------------------------------------------------------------
// Output projection: out[r][o] = sum_{h,e} rep[r][h*64+e] * Wo[h][o][e].
// Wo chunk (64o x 64k) fp32->bf16 staged in LDS per k-chunk (=head),
// shared by all waves.  A=Wo(LDS), B=rep(global hi/lo) -> float4 stores.
// ---------------------------------------------------------------------------
__global__ __launch_bounds__(256) void outproj_kernel(
    const u16* __restrict__ RepH, const u16* __restrict__ RepL,
    const float* __restrict__ Wo, float* __restrict__ out)
{
  __shared__ u16 wt[64][72];

  const int t = threadIdx.x, w = t >> 6, lane = t & 63;
  const int jl = lane & 15, q = lane >> 4;
  const int rtile = blockIdx.x, otile = blockIdx.y;
  const int r0 = rtile * 64 + w * 16;

  const u16* ah_row = RepH + (size_t)(r0 + jl) * DD;
  const u16* al_row = RepL + (size_t)(r0 + jl) * DD;

  f32x4 acc[4];
  #pragma unroll
  for (int i = 0; i < 4; ++i) acc[i] = (f32x4){0.f,0.f,0.f,0.f};

  for (int hc = 0; hc < 8; ++hc) {
    __syncthreads();
    #pragma unroll
    for (int it = 0; it < 4; ++it) {
      const int o = it * 16 + (t >> 4), c = (t & 15) * 4;
      float4 f = *(const float4*)&Wo[((size_t)hc * DD + otile * 64 + o) * EE + c];
      *(uint2*)&wt[o][c] = make_uint2(pk2(f.x, f.y), pk2(f.z, f.w));
    }
    __syncthreads();
    #pragma unroll
    for (int kc2 = 0; kc2 < 2; ++kc2) {
      const int k0 = hc * 64 + kc2 * 32 + q * 8;
      bf16x8 bhf = ld_frag(ah_row + k0);
      bf16x8 blf = ld_frag(al_row + k0);
      #pragma unroll
      for (int os = 0; os < 4; ++os) {
        bf16x8 wf = ld_frag(&wt[os * 16 + jl][kc2 * 32 + q * 8]);
        acc[os] = MFMA(wf, bhf, acc[os]);
        acc[os] = MFMA(wf, blf, acc[os]);
      }
    }
  }

  #pragma unroll
  for (int os = 0; os < 4; ++os) {   // D row = o (r-consecutive), D col = rep-row
    float4 o4 = make_float4(acc[os][0], acc[os][1], acc[os][2], acc[os][3]);
    *(float4*)&out[(size_t)(r0 + jl) * DD + otile * 64 + os * 16 + q * 4] = o4;
  }
}

// ---------------------------------------------------------------------------
extern "C" void kernel_launch(void* const* d_in, const int* in_sizes, int n_in,
                              void* d_out, int out_size, void* d_ws, size_t ws_size,
                              hipStream_t stream)
{
  const float* x1 = (const float*)d_in[0];
  const float* x2 = (const float*)d_in[1];
  const float* vv = (const float*)d_in[2];
  const float* Wq = (const float*)d_in[3];
  const float* Wk = (const float*)d_in[4];
  const float* Wv = (const float*)d_in[5];
  const float* Wo = (const float*)d_in[6];
  float* out = (float*)d_out;

  char* W = (char*)d_ws;                       // 48 MB total
  u16* Qb   = (u16*)(W);
  u16* Kb   = (u16*)(W + 1ul * 8388608);
  u16* Vth  = (u16*)(W + 2ul * 8388608);
  u16* Vtl  = (u16*)(W + 3ul * 8388608);
  u16* RepH = (u16*)(W + 4ul * 8388608);
  u16* RepL = (u16*)(W + 5ul * 8388608);

  qkvproj_kernel<<<dim3(32, 32, 3), 256, 0, stream>>>(x1, x2, vv, Wq, Wk, Wv,
                                                      Qb, Kb, Vth, Vtl);
  attn_kernel   <<<dim3(1024), 256, 0, stream>>>(Qb, Kb, Vth, Vtl, RepH, RepL);
  outproj_kernel<<<dim3(128, 8), 256, 0, stream>>>(RepH, RepL, Wo, out);
}